// Round 4
// baseline (631.926 us; speedup 1.0000x reference)
//
#include <hip/hip_runtime.h>
#include <stdint.h>

// Self-attention block: B=16, C=O=512, W=H=64 (N=4096 pixels)
// Pipeline: convert weights -> [transpose+cvt X -> proj GEMM] x3 -> scores+exp -> reduce D -> out
//
// Full-ws layout (needs ~194.3 MiB):
//   Wb bf16 (1.5MiB) @0 | Qp/E @2MiB | Kp @+64MiB | Vp @+128MiB | Dinv @+192MiB
//   d_out (128 MiB) doubles as Xt scratch (64MiB) until the final kernel overwrites it.
// If ws_size is smaller, fall back to batch-chunked processing (nb batches/chunk,
// 17 MiB per batch inside ws) — same kernels, pointer offsets + grid.z.

typedef __attribute__((ext_vector_type(8))) short bhalf8;
typedef __attribute__((ext_vector_type(4))) float floatx4;

#define INV_SQRT_C 0.04419417382415922f   // 1/sqrt(512)

__device__ __forceinline__ uint16_t f2bf(float f) {
  union { float f; uint32_t u; } v; v.f = f;
  uint32_t r = v.u + 0x7FFFu + ((v.u >> 16) & 1u);   // RNE
  return (uint16_t)(r >> 16);
}
__device__ __forceinline__ float bf2f(uint16_t u) {
  union { uint32_t u; float f; } v; v.u = ((uint32_t)u) << 16; return v.f;
}

// ---------------- weights fp32 -> bf16 (q gets 1/sqrt(C) folded in) ----------------
__global__ __launch_bounds__(256) void kconvw(const float* __restrict__ wq,
                                              const float* __restrict__ wk,
                                              const float* __restrict__ wv,
                                              uint16_t* __restrict__ Wb) {
  int i = blockIdx.x * 256 + threadIdx.x;   // 3*65536 float4 groups
  int p = i >> 16;
  int r = i & 65535;
  const float* src = (p == 0) ? wq : (p == 1) ? wk : wv;
  float sc = (p == 0) ? INV_SQRT_C : 1.0f;
  float4 v = ((const float4*)src)[r];
  ushort4 o;
  o.x = f2bf(v.x * sc); o.y = f2bf(v.y * sc); o.z = f2bf(v.z * sc); o.w = f2bf(v.w * sc);
  ((ushort4*)(Wb + (size_t)p * 262144))[r] = o;
}

// ---------------- X [b][512 c][4096 n] f32  ->  Xt [b][4096 n][512 c] bf16 ----------------
__global__ __launch_bounds__(256) void ktrans(const float* __restrict__ X, uint16_t* __restrict__ Xt) {
  __shared__ float tile[64][65];
  int b = blockIdx.z;
  int c0 = blockIdx.y * 64, n0 = blockIdx.x * 64;
  int tx = threadIdx.x & 15, ty = threadIdx.x >> 4;
  const float* src = X + ((size_t)b * 512 + c0) * 4096 + n0;
#pragma unroll
  for (int i = 0; i < 4; ++i) {
    int c = ty + i * 16;
    float4 v = *(const float4*)(src + (size_t)c * 4096 + tx * 4);
    tile[c][tx * 4 + 0] = v.x; tile[c][tx * 4 + 1] = v.y;
    tile[c][tx * 4 + 2] = v.z; tile[c][tx * 4 + 3] = v.w;
  }
  __syncthreads();
  uint16_t* dst = Xt + ((size_t)b * 4096 + n0) * 512 + c0;
#pragma unroll
  for (int i = 0; i < 4; ++i) {
    int n = ty + i * 16;
    ushort4 o;
    o.x = f2bf(tile[tx * 4 + 0][n]); o.y = f2bf(tile[tx * 4 + 1][n]);
    o.z = f2bf(tile[tx * 4 + 2][n]); o.w = f2bf(tile[tx * 4 + 3][n]);
    *(ushort4*)(dst + (size_t)n * 512 + tx * 4) = o;
  }
}

// ---------------- projection GEMM: Y[b][o][n] = bf16( W[o][:] . Xt[b][n][:] + bias[o]*bscale ) ----------------
// 128x128 tile, BK=64, 4 waves, 2-phase global_load_lds pipeline, XOR-swizzled staging source (rule #21).
__global__ __launch_bounds__(256, 2) void kproj(const uint16_t* __restrict__ Xt,
                                                const uint16_t* __restrict__ Wmat,
                                                const float* __restrict__ bias,
                                                float bscale,
                                                uint16_t* __restrict__ Y) {
  __shared__ __align__(16) uint16_t As[2][128 * 64];
  __shared__ __align__(16) uint16_t Bs[2][128 * 64];
  int b = blockIdx.z;
  int o0 = blockIdx.y * 128, n0 = blockIdx.x * 128;
  int t = threadIdx.x;
  int lane = t & 63, wave = t >> 6;
  int wr = wave >> 1, wc = wave & 1;
  const uint16_t* Xb = Xt + (size_t)b * 4096 * 512 + (size_t)n0 * 512;
  const uint16_t* Wt = Wmat + (size_t)o0 * 512;
  Y += (size_t)b * 512 * 4096;

  const int schunk = (lane & 7) ^ ((lane >> 3) & 7);   // inverse of read-side XOR (row&7 == lane>>3)

  auto stage = [&](int buf, int kc) {
#pragma unroll
    for (int i = 0; i < 4; ++i) {
      int r = wave * 32 + i * 8 + (lane >> 3);
      const uint16_t* sa = Wt + (size_t)r * 512 + kc * 64 + schunk * 8;
      const uint16_t* sb = Xb + (size_t)r * 512 + kc * 64 + schunk * 8;
      uint16_t* da = &As[buf][(wave * 32 + i * 8) * 64];
      uint16_t* db = &Bs[buf][(wave * 32 + i * 8) * 64];
      __builtin_amdgcn_global_load_lds((const __attribute__((address_space(1))) uint32_t*)sa,
                                       (__attribute__((address_space(3))) uint32_t*)da, 16, 0, 0);
      __builtin_amdgcn_global_load_lds((const __attribute__((address_space(1))) uint32_t*)sb,
                                       (__attribute__((address_space(3))) uint32_t*)db, 16, 0, 0);
    }
  };

  floatx4 acc[4][4];
#pragma unroll
  for (int mt = 0; mt < 4; ++mt)
#pragma unroll
    for (int nt = 0; nt < 4; ++nt) acc[mt][nt] = (floatx4)0.0f;

  stage(0, 0);
  __syncthreads();
  int cur = 0;
  const int g = lane >> 4, m = lane & 15;
  for (int kc = 0; kc < 8; ++kc) {
    if (kc < 7) stage(cur ^ 1, kc + 1);
    const char* Ab = (const char*)&As[cur][0];
    const char* Bb = (const char*)&Bs[cur][0];
#pragma unroll
    for (int kh = 0; kh < 2; ++kh) {
      int cI = kh * 4 + g;
      int swz = (cI ^ (m & 7)) * 16;
      bhalf8 av[4], bv_[4];
#pragma unroll
      for (int mt = 0; mt < 4; ++mt) {
        int row = wr * 64 + mt * 16 + m;
        av[mt] = *(const bhalf8*)(Ab + row * 128 + swz);
      }
#pragma unroll
      for (int nt = 0; nt < 4; ++nt) {
        int row = wc * 64 + nt * 16 + m;
        bv_[nt] = *(const bhalf8*)(Bb + row * 128 + swz);
      }
#pragma unroll
      for (int mt = 0; mt < 4; ++mt)
#pragma unroll
        for (int nt = 0; nt < 4; ++nt)
          acc[mt][nt] = __builtin_amdgcn_mfma_f32_16x16x32_bf16(av[mt], bv_[nt], acc[mt][nt], 0, 0, 0);
    }
    __syncthreads();
    cur ^= 1;
  }
  // epilogue: + bias, cvt bf16, store (D frag: row=(lane>>4)*4+r, col=lane&15)
#pragma unroll
  for (int mt = 0; mt < 4; ++mt) {
    int orow = o0 + wr * 64 + mt * 16 + g * 4;
    float bvv[4];
#pragma unroll
    for (int r = 0; r < 4; ++r) bvv[r] = bias[orow + r] * bscale;
#pragma unroll
    for (int nt = 0; nt < 4; ++nt) {
      int n = n0 + wc * 64 + nt * 16 + m;
#pragma unroll
      for (int r = 0; r < 4; ++r)
        Y[(size_t)(orow + r) * 4096 + n] = f2bf(acc[mt][nt][r] + bvv[r]);
    }
  }
}

// ---------------- scores: E[b,o] = exp( Qp[b,o] @ Kp[b,o] )  (scale pre-folded into Qp) ----------------
// E written in-place over Qp (block fully stages its own Q tile first).
__global__ __launch_bounds__(256) void kscores(const uint16_t* Qp,
                                               const uint16_t* __restrict__ Kp,
                                               uint16_t* E) {
  __shared__ __align__(16) uint16_t Ql[64 * 72];   // [w][h], padded rows (144B)
  __shared__ __align__(16) uint16_t Kt[64 * 72];   // [x][h]  (transposed K tile)
  int bo = blockIdx.x;
  const uint16_t* Qs = Qp + (size_t)bo * 4096;
  const uint16_t* Ks = Kp + (size_t)bo * 4096;
  int t = threadIdx.x;
#pragma unroll
  for (int p = 0; p < 2; ++p) {
    int rr = (t >> 3) + p * 32;     // storage row (w for Q, h for K)
    int cc = (t & 7) * 8;           // storage col start
    uint4 qv = *(const uint4*)(Qs + rr * 64 + cc);
    *(uint4*)((char*)Ql + rr * 144 + cc * 2) = qv;
    uint4 kv = *(const uint4*)(Ks + rr * 64 + cc);
    const uint16_t* k16 = (const uint16_t*)&kv;
#pragma unroll
    for (int j = 0; j < 8; ++j) Kt[(cc + j) * 72 + rr] = k16[j];
  }
  __syncthreads();
  int lane = t & 63, wvv = t >> 6;
  int g = lane >> 4, m = lane & 15;
  floatx4 acc[4];
#pragma unroll
  for (int nt = 0; nt < 4; ++nt) acc[nt] = (floatx4)0.0f;
#pragma unroll
  for (int kh = 0; kh < 2; ++kh) {
    int co = (kh * 32 + g * 8) * 2;
    bhalf8 a = *(const bhalf8*)((const char*)Ql + (wvv * 16 + m) * 144 + co);
#pragma unroll
    for (int nt = 0; nt < 4; ++nt) {
      bhalf8 bb = *(const bhalf8*)((const char*)Kt + (nt * 16 + m) * 144 + co);
      acc[nt] = __builtin_amdgcn_mfma_f32_16x16x32_bf16(a, bb, acc[nt], 0, 0, 0);
    }
  }
  uint16_t* Eo = E + (size_t)bo * 4096;
#pragma unroll
  for (int nt = 0; nt < 4; ++nt) {
    int x = nt * 16 + m;
#pragma unroll
    for (int r = 0; r < 4; ++r) {
      int w = wvv * 16 + g * 4 + r;
      Eo[w * 64 + x] = f2bf(__expf(acc[nt][r]));
    }
  }
}

// ---------------- Dinv[b,wx] = 1 / sum_o E[b,o,wx]  (4-way o-split per block for TLP) ----------------
__global__ __launch_bounds__(256) void kreduce(const uint16_t* __restrict__ E, float* __restrict__ Dinv) {
  __shared__ float part[4][64];
  int b = blockIdx.x >> 6;                 // nb batches x 64 pixel-groups
  int p0 = (blockIdx.x & 63) * 64;
  int px = threadIdx.x & 63, og = threadIdx.x >> 6;
  const uint16_t* p = E + ((size_t)b * 512 + (size_t)og * 128) * 4096 + p0 + px;
  float s = 0.f;
#pragma unroll 8
  for (int o = 0; o < 128; ++o) s += bf2f(p[(size_t)o * 4096]);
  part[og][px] = s;
  __syncthreads();
  if (threadIdx.x < 64) {
    int i = threadIdx.x;
    Dinv[(size_t)b * 4096 + p0 + i] =
        1.0f / (part[0][i] + part[1][i] + part[2][i] + part[3][i]);
  }
}

// ---------------- out[b,o] = (E[b,o] * Dinv[b]) @ V[b,o] ----------------
__global__ __launch_bounds__(256) void kout(const uint16_t* __restrict__ E,
                                            const uint16_t* __restrict__ Vp,
                                            const float* __restrict__ Dinv,
                                            float* __restrict__ Out) {
  __shared__ __align__(16) uint16_t Al[64 * 72];   // attn [w][x], padded
  __shared__ __align__(16) uint16_t Vt[64 * 72];   // [h][x]  (transposed V tile)
  int bo = blockIdx.x;
  int b = bo >> 9;
  const uint16_t* Es = E + (size_t)bo * 4096;
  const uint16_t* Vs = Vp + (size_t)bo * 4096;
  const float* Ds = Dinv + (size_t)b * 4096;
  int t = threadIdx.x;
#pragma unroll
  for (int p = 0; p < 2; ++p) {
    int rr = (t >> 3) + p * 32;
    int cc = (t & 7) * 8;
    uint4 ev = *(const uint4*)(Es + rr * 64 + cc);
    const uint16_t* e16 = (const uint16_t*)&ev;
    float4 d0 = *(const float4*)(Ds + rr * 64 + cc);
    float4 d1 = *(const float4*)(Ds + rr * 64 + cc + 4);
    uint16_t a8[8];
    a8[0] = f2bf(bf2f(e16[0]) * d0.x); a8[1] = f2bf(bf2f(e16[1]) * d0.y);
    a8[2] = f2bf(bf2f(e16[2]) * d0.z); a8[3] = f2bf(bf2f(e16[3]) * d0.w);
    a8[4] = f2bf(bf2f(e16[4]) * d1.x); a8[5] = f2bf(bf2f(e16[5]) * d1.y);
    a8[6] = f2bf(bf2f(e16[6]) * d1.z); a8[7] = f2bf(bf2f(e16[7]) * d1.w);
    *(uint4*)((char*)Al + rr * 144 + cc * 2) = *(const uint4*)a8;
    uint4 vv = *(const uint4*)(Vs + rr * 64 + cc);
    const uint16_t* v16 = (const uint16_t*)&vv;
#pragma unroll
    for (int j = 0; j < 8; ++j) Vt[(cc + j) * 72 + rr] = v16[j];
  }
  __syncthreads();
  int lane = t & 63, wvv = t >> 6;
  int g = lane >> 4, m = lane & 15;
  floatx4 acc[4];
#pragma unroll
  for (int nt = 0; nt < 4; ++nt) acc[nt] = (floatx4)0.0f;
#pragma unroll
  for (int kh = 0; kh < 2; ++kh) {
    int co = (kh * 32 + g * 8) * 2;
    bhalf8 a = *(const bhalf8*)((const char*)Al + (wvv * 16 + m) * 144 + co);
#pragma unroll
    for (int nt = 0; nt < 4; ++nt) {
      bhalf8 bb = *(const bhalf8*)((const char*)Vt + (nt * 16 + m) * 144 + co);
      acc[nt] = __builtin_amdgcn_mfma_f32_16x16x32_bf16(a, bb, acc[nt], 0, 0, 0);
    }
  }
  float* Oo = Out + (size_t)bo * 4096;
#pragma unroll
  for (int nt = 0; nt < 4; ++nt) {
    int h = nt * 16 + m;
#pragma unroll
    for (int r = 0; r < 4; ++r) {
      int w = wvv * 16 + g * 4 + r;
      Oo[w * 64 + h] = acc[nt][r];
    }
  }
}

extern "C" void kernel_launch(void* const* d_in, const int* in_sizes, int n_in,
                              void* d_out, int out_size, void* d_ws, size_t ws_size,
                              hipStream_t stream) {
  const float* q  = (const float*)d_in[0];
  const float* k  = (const float*)d_in[1];
  const float* v  = (const float*)d_in[2];
  const float* wq = (const float*)d_in[3];
  const float* bq = (const float*)d_in[4];
  const float* wk = (const float*)d_in[5];
  const float* bk = (const float*)d_in[6];
  const float* wv = (const float*)d_in[7];
  const float* bv = (const float*)d_in[8];

  const size_t MiB = 1ull << 20;
  const size_t BATCH_ELEMS = 512ull * 4096;          // per-batch Q/K/V bf16 elems (4 MiB)
  uint16_t* Wb = (uint16_t*)d_ws;                    // 3*512*512 bf16 = 1.5 MiB @ ws+0

  if (ws_size < 4 * MiB) return;                     // cannot even hold weights safely
  kconvw<<<768, 256, 0, stream>>>(wq, wk, wv, Wb);

  if (ws_size >= 195 * MiB) {
    // ---------- full path: all 16 batches at once; Xt scratch lives in d_out ----------
    uint16_t* Qp = (uint16_t*)((char*)d_ws + 2 * MiB);   // 64 MiB (later E)
    uint16_t* Kp = Qp + 16 * BATCH_ELEMS;                // 64 MiB
    uint16_t* Vp = Kp + 16 * BATCH_ELEMS;                // 64 MiB
    float*  Dinv = (float*)(Vp + 16 * BATCH_ELEMS);      // 256 KiB
    uint16_t* Xt = (uint16_t*)d_out;                     // 64 MiB scratch inside 128 MiB d_out

    dim3 gT(64, 8, 16);   // n-tiles, c-tiles, b
    dim3 gG(32, 4, 16);   // n-tiles, o-tiles, b
    ktrans<<<gT, 256, 0, stream>>>(q, Xt);
    kproj <<<gG, 256, 0, stream>>>(Xt, Wb,              bq, INV_SQRT_C, Qp);
    ktrans<<<gT, 256, 0, stream>>>(k, Xt);
    kproj <<<gG, 256, 0, stream>>>(Xt, Wb + 262144,     bk, 1.0f,       Kp);
    ktrans<<<gT, 256, 0, stream>>>(v, Xt);
    kproj <<<gG, 256, 0, stream>>>(Xt, Wb + 2 * 262144, bv, 1.0f,       Vp);

    kscores<<<8192, 256, 0, stream>>>(Qp, Kp, Qp);       // E overwrites Qp
    kreduce<<<1024, 256, 0, stream>>>(Qp, Dinv);
    kout  <<<8192, 256, 0, stream>>>(Qp, Vp, Dinv, (float*)d_out);
    return;
  }

  // ---------- chunked fallback: nb batches per chunk, everything inside ws ----------
  int nb = (int)((ws_size - 2 * MiB) / (17 * MiB));
  if (nb < 1) return;                                    // loud (verification) failure, no OOB
  if (nb > 16) nb = 16;
  char* base = (char*)d_ws + 2 * MiB;
  uint16_t* Xt  = (uint16_t*)base;                       // nb*4 MiB
  uint16_t* Qp  = Xt + (size_t)nb * BATCH_ELEMS;         // nb*4 MiB (later E)
  uint16_t* Kp  = Qp + (size_t)nb * BATCH_ELEMS;         // nb*4 MiB
  uint16_t* Vp  = Kp + (size_t)nb * BATCH_ELEMS;         // nb*4 MiB
  float*   Dinv = (float*)(Vp + (size_t)nb * BATCH_ELEMS);  // nb*16 KiB

  for (int b0 = 0; b0 < 16; b0 += nb) {
    int cnb = (16 - b0 < nb) ? (16 - b0) : nb;
    const float* qb = q + (size_t)b0 * 512 * 4096;
    const float* kb = k + (size_t)b0 * 512 * 4096;
    const float* vb = v + (size_t)b0 * 512 * 4096;
    dim3 gT(64, 8, cnb);
    dim3 gG(32, 4, cnb);
    ktrans<<<gT, 256, 0, stream>>>(qb, Xt);
    kproj <<<gG, 256, 0, stream>>>(Xt, Wb,              bq, INV_SQRT_C, Qp);
    ktrans<<<gT, 256, 0, stream>>>(kb, Xt);
    kproj <<<gG, 256, 0, stream>>>(Xt, Wb + 262144,     bk, 1.0f,       Kp);
    ktrans<<<gT, 256, 0, stream>>>(vb, Xt);
    kproj <<<gG, 256, 0, stream>>>(Xt, Wb + 2 * 262144, bv, 1.0f,       Vp);

    kscores<<<cnb * 512, 256, 0, stream>>>(Qp, Kp, Qp);
    kreduce<<<cnb * 64,  256, 0, stream>>>(Qp, Dinv);
    kout  <<<cnb * 512, 256, 0, stream>>>(Qp, Vp, Dinv,
                                          (float*)d_out + (size_t)b0 * 512 * 4096);
  }
}